// Round 5
// baseline (5764.966 us; speedup 1.0000x reference)
//
#include <hip/hip_runtime.h>
#include <cmath>

// T=512, B=32, D=1024, H=1024, 3H=3072
// d_out: outputs (512*32*1024) ++ outputs[-1] (32*1024) ++ h_last (32*1024)  fp32

typedef short s8v  __attribute__((ext_vector_type(8)));   // 8 x bf16 (raw bits)
typedef float f4v  __attribute__((ext_vector_type(4)));   // MFMA accumulator

#define NB 64       // blocks in the GRU grid
#define GUARD 16384 // bounded-spin: degrade to wrong-answer instead of hanging

__device__ __forceinline__ short f2bf(float f) {
    return __builtin_bit_cast(short, (__bf16)f);          // RNE convert
}
__device__ __forceinline__ float bf2f(short s) {
    return (float)__builtin_bit_cast(__bf16, s);
}

// ---------------------------------------------------------------------------
// Transpose W [1024][3072] fp32  ->  Wt [3072][1024] bf16.
// ---------------------------------------------------------------------------
__global__ __launch_bounds__(256) void k_transpose_bf16(
        const float* __restrict__ W, short* __restrict__ Wt) {
    __shared__ short Ls[32][72];
    int bk = blockIdx.x & 31;
    int bn = blockIdx.x >> 5;
    int k0 = bk * 32, n0 = bn * 64;
    int tid = threadIdx.x;
    {
        int r  = tid >> 3;
        int c0 = (tid & 7) * 8;
        const float* src = W + (size_t)(k0 + r) * 3072 + n0 + c0;
        float4 f0 = *reinterpret_cast<const float4*>(src);
        float4 f1 = *reinterpret_cast<const float4*>(src + 4);
        Ls[r][c0+0] = f2bf(f0.x); Ls[r][c0+1] = f2bf(f0.y);
        Ls[r][c0+2] = f2bf(f0.z); Ls[r][c0+3] = f2bf(f0.w);
        Ls[r][c0+4] = f2bf(f1.x); Ls[r][c0+5] = f2bf(f1.y);
        Ls[r][c0+6] = f2bf(f1.z); Ls[r][c0+7] = f2bf(f1.w);
    }
    __syncthreads();
    {
        int j   = tid >> 2;
        int kk0 = (tid & 3) * 8;
        s8v v;
        #pragma unroll
        for (int s = 0; s < 8; ++s) v[s] = Ls[kk0 + s][j];
        *reinterpret_cast<s8v*>(Wt + (size_t)(n0 + j) * 1024 + k0 + kk0) = v;
    }
}

// ---------------------------------------------------------------------------
// gi = X @ W_ih.  M=16384, N=3072, K=1024.  Output bf16.
// ---------------------------------------------------------------------------
__global__ __launch_bounds__(256) void k_gemm_gi(
        const float* __restrict__ X, const short* __restrict__ Wt,
        short* __restrict__ gi) {
    __shared__ short As[64][40];
    __shared__ short Bs[64][40];
    int bm = blockIdx.x & 255;
    int bn = blockIdx.x >> 8;
    int m0 = bm * 64, n0 = bn * 64;
    int tid = threadIdx.x;
    int wid = tid >> 6, l = tid & 63;
    int wm = wid >> 1, wn = wid & 1;
    int lr = l & 15, q = l >> 4;
    f4v acc[2][2] = {};
    int sr = tid >> 2;
    int sc = (tid & 3) * 8;

    for (int kc = 0; kc < 1024; kc += 32) {
        const float* asrc = X + (size_t)(m0 + sr) * 1024 + kc + sc;
        float4 f0 = *reinterpret_cast<const float4*>(asrc);
        float4 f1 = *reinterpret_cast<const float4*>(asrc + 4);
        s8v av;
        av[0]=f2bf(f0.x); av[1]=f2bf(f0.y); av[2]=f2bf(f0.z); av[3]=f2bf(f0.w);
        av[4]=f2bf(f1.x); av[5]=f2bf(f1.y); av[6]=f2bf(f1.z); av[7]=f2bf(f1.w);
        *reinterpret_cast<s8v*>(&As[sr][sc]) = av;
        *reinterpret_cast<s8v*>(&Bs[sr][sc]) =
            *reinterpret_cast<const s8v*>(Wt + (size_t)(n0 + sr) * 1024 + kc + sc);
        __syncthreads();
        s8v a0 = *reinterpret_cast<const s8v*>(&As[wm*32 +  0 + lr][q*8]);
        s8v a1 = *reinterpret_cast<const s8v*>(&As[wm*32 + 16 + lr][q*8]);
        s8v b0 = *reinterpret_cast<const s8v*>(&Bs[wn*32 +  0 + lr][q*8]);
        s8v b1 = *reinterpret_cast<const s8v*>(&Bs[wn*32 + 16 + lr][q*8]);
        acc[0][0] = __builtin_amdgcn_mfma_f32_16x16x32_bf16(a0, b0, acc[0][0], 0,0,0);
        acc[0][1] = __builtin_amdgcn_mfma_f32_16x16x32_bf16(a0, b1, acc[0][1], 0,0,0);
        acc[1][0] = __builtin_amdgcn_mfma_f32_16x16x32_bf16(a1, b0, acc[1][0], 0,0,0);
        acc[1][1] = __builtin_amdgcn_mfma_f32_16x16x32_bf16(a1, b1, acc[1][1], 0,0,0);
        __syncthreads();
    }
    #pragma unroll
    for (int ms = 0; ms < 2; ++ms)
      #pragma unroll
      for (int ns = 0; ns < 2; ++ns) {
        int m = m0 + wm*32 + ms*16 + q*4;
        int n = n0 + wn*32 + ns*16 + lr;
        #pragma unroll
        for (int i = 0; i < 4; ++i)
            gi[(size_t)(m + i) * 3072 + n] = f2bf(acc[ms][ns][i]);
      }
}

// ---------------------------------------------------------------------------
// GRU recurrence v8 — self-tagged u64 h quanta, round-0-proven atomics only.
//
// h exchange quantum: u64 = { 2 x bf16 h (high dword) | step tag (low dword) }.
// Naturally-aligned 64-bit accesses are single-copy atomic (LLVM AMDGPU
// memory model) -> tag and data can never tear apart (v6's bug).  All
// loads/stores use __hip_atomic_load/store RELAXED+AGENT — the exact
// instruction semantics the round-0 PASSING kernel used for h and flags
// (no hand-rolled sc0/sc1 asm, no asm-pinned 256-reg bursts: v7b's deltas).
//
// hb3: [2 parity][32 rows][512 u64]  (256 KiB; memset(0) == valid step-0
// state: tag 0 + h = 0).  flags: [2][64] per-(half, block) step counters.
//
// Per wave, step t:
//   1. consume in 4 batches of 32 u64: spin { load batch, per-u64 compare
//      tag==t, __all }. Data arrival IS the signal (no flag RT, no producer
//      ACK). Batches 1-3 arrive under the MFMAs of earlier batches; 32-u64
//      batches keep VGPR pressure sane (~64 regs vs v7b's 256).
//   2. flag prefetch issued before compute; latency hides under MFMA.
//   3. MFMA (acc += over batches) + gates -> h(t+1).
//   4. GATE (1<=t<511): all 64 own-half flags >= t (steady state: raised a
//      full step ago -> free). Writer overwrites tag-(t-1) u64s with t+1
//      only after all own-half waves finished step t-1; a wave still
//      polling tag t has flag t < t+1, blocking every writer's NEXT gate,
//      so tags in a polled parity are in {t-2, t}: per-u64 compare==t can
//      only accept fresh data. Deadlock-free by induction.
//   5. publish 2 tagged u64 atomic stores + flag store. NO waitcnt.
//   6. out stores + gi/pad prefetch strictly after publish.
// Bounded spins (GUARD) degrade any unforeseen bug to a fast wrong answer.
// ---------------------------------------------------------------------------
__global__ __launch_bounds__(128, 1) void k_gru(
        const float* __restrict__ pad,   // [512][32]
        const short* __restrict__ gi,    // [16384][3072] bf16 (no bias)
        const short* __restrict__ Whht,  // [3072][1024] bf16
        const float* __restrict__ b_ih,  // [3072]
        const float* __restrict__ b_hh,  // [3072]
        unsigned long long* __restrict__ hb3,  // [2][32][512] tagged u64 (zeroed)
        unsigned* __restrict__ flags,    // [2][64] step flags (pre-zeroed)
        float* __restrict__ out) {
    extern __shared__ short wlds[];      // 48 rows x 1024, stride 1032 shorts
    const int WS = 1032;
    int bid = blockIdx.x;                // 0..63
    int j0  = bid * 16;
    int tid = threadIdx.x;               // 0..127
    int w   = tid >> 6;                  // batch half
    int l   = tid & 63, lr = l & 15, q = l >> 4;

    // Stage weight slice: rows (gate g, col c) x 1024 shorts. (both waves)
    for (int idx = tid; idx < 48 * 128; idx += 128) {
        int row = idx >> 7;
        int ko  = (idx & 127) * 8;
        int g = row >> 4, c = row & 15;
        *reinterpret_cast<s8v*>(&wlds[(g * 16 + c) * WS + ko]) =
            *reinterpret_cast<const s8v*>(Whht + (size_t)(g * 1024 + j0 + c) * 1024 + ko);
    }
    __syncthreads();                     // weights ready; last sync in kernel

    int jq = j0 + q * 4;                 // first of this lane's 4 j-cols
    int b  = w * 16 + lr;                // this lane's batch row
    f4v sbr = *reinterpret_cast<const f4v*>(b_ih + jq)
            + *reinterpret_cast<const f4v*>(b_hh + jq);
    f4v sbz = *reinterpret_cast<const f4v*>(b_ih + 1024 + jq)
            + *reinterpret_cast<const f4v*>(b_hh + 1024 + jq);
    f4v sbn_i = *reinterpret_cast<const f4v*>(b_ih + 2048 + jq);
    f4v sbn_h = *reinterpret_cast<const f4v*>(b_hh + 2048 + jq);
    const short* w_r = &wlds[(0 * 16 + lr) * WS + q * 8];
    const short* w_z = &wlds[(1 * 16 + lr) * WS + q * 8];
    const short* w_n = &wlds[(2 * 16 + lr) * WS + q * 8];
    float hp[4] = {0.f, 0.f, 0.f, 0.f};

    const unsigned* myflags = flags + w * 64 + l;   // own-half flag of block l

    union u64s { unsigned long long u; short s[4]; };
    u64s gr_, gz_, gn_; float pv;
    {   // prefetch gi/pad for t=0
        const short* gp = gi + (size_t)b * 3072 + jq;
        gr_.u = *reinterpret_cast<const unsigned long long*>(gp);
        gz_.u = *reinterpret_cast<const unsigned long long*>(gp + 1024);
        gn_.u = *reinterpret_cast<const unsigned long long*>(gp + 2048);
        pv = pad[b];
    }

    for (int t = 0; t < 512; ++t) {
        unsigned tg = (unsigned)t;
        // lane (b, q) needs h[b][k], k in {it*32 + q*8 .. +8}, it = 0..31
        //   -> u64 indices it*16 + q*4 + j, j = 0..3.
        const unsigned long long* hrow =
            hb3 + (size_t)((t & 1) * 32 + b) * 512 + q * 4;

        // ---- 2. flag prefetch (used by the gate after compute) ----
        unsigned flg = __hip_atomic_load(myflags, __ATOMIC_RELAXED,
                                         __HIP_MEMORY_SCOPE_AGENT);

        // ---- 1+3. batched consume + compute ----
        f4v ar = {0,0,0,0}, az = {0,0,0,0}, an = {0,0,0,0};
        #pragma unroll
        for (int bb = 0; bb < 4; ++bb) {
            unsigned long long hv[32];
            int guard = 0;
            for (;;) {
                #pragma unroll
                for (int ii = 0; ii < 8; ++ii)
                    #pragma unroll
                    for (int j = 0; j < 4; ++j)
                        hv[ii*4 + j] = __hip_atomic_load(
                            hrow + (bb*8 + ii) * 16 + j,
                            __ATOMIC_RELAXED, __HIP_MEMORY_SCOPE_AGENT);
                int ok = 1;
                #pragma unroll
                for (int k2 = 0; k2 < 32; ++k2)
                    ok &= (int)((unsigned)hv[k2] == tg);
                if (__all(ok)) break;
                if (++guard > GUARD) break;      // anti-hang: degrade, don't die
                __builtin_amdgcn_s_sleep(1);
            }
            #pragma unroll
            for (int ii = 0; ii < 8; ++ii) {
                union { unsigned u[4]; s8v v; } hx;
                #pragma unroll
                for (int j = 0; j < 4; ++j)
                    hx.u[j] = (unsigned)(hv[ii*4 + j] >> 32);
                int it = bb * 8 + ii;
                s8v r8 = *reinterpret_cast<const s8v*>(w_r + it * 32);
                s8v z8 = *reinterpret_cast<const s8v*>(w_z + it * 32);
                s8v n8 = *reinterpret_cast<const s8v*>(w_n + it * 32);
                ar = __builtin_amdgcn_mfma_f32_16x16x32_bf16(r8, hx.v, ar, 0,0,0);
                az = __builtin_amdgcn_mfma_f32_16x16x32_bf16(z8, hx.v, az, 0,0,0);
                an = __builtin_amdgcn_mfma_f32_16x16x32_bf16(n8, hx.v, an, 0,0,0);
            }
        }

        #pragma unroll
        for (int i = 0; i < 4; ++i) {
            float xr = bf2f(gr_.s[i]) + ar[i] + sbr[i];
            float xz = bf2f(gz_.s[i]) + az[i] + sbz[i];
            float r  = __builtin_amdgcn_rcpf(1.f + __expf(-xr));
            float z  = __builtin_amdgcn_rcpf(1.f + __expf(-xz));
            float xn = bf2f(gn_.s[i]) + sbn_i[i] + r * (an[i] + sbn_h[i]);
            float e2 = __expf(2.f * xn);
            float n  = 1.f - 2.f * __builtin_amdgcn_rcpf(1.f + e2);   // tanh
            float hnv = (1.f - z) * n + z * hp[i];
            hnv = pv * hp[i] + (1.f - pv) * hnv;
            hp[i] = hnv;
        }

        // ---- 4. overwrite-safety gate (steady state: already satisfied) ----
        if (t && t < 511) {
            unsigned uT = (unsigned)t;
            int g2 = 0;
            while (!__all((int)(flg >= uT))) {
                if (++g2 > GUARD) break;         // anti-hang
                __builtin_amdgcn_s_sleep(1);
                flg = __hip_atomic_load(myflags, __ATOMIC_RELAXED,
                                        __HIP_MEMORY_SCOPE_AGENT);
            }
        }

        int rowg = t * 32 + b;

        // ---- 5. publish: 2 tagged u64 atomic stores + flag. NO waitcnt. ----
        if (t < 511) {
            unsigned long long tg1 = (unsigned long long)(t + 1);
            unsigned p01 = ((unsigned)(unsigned short)f2bf(hp[1]) << 16)
                         |  (unsigned)(unsigned short)f2bf(hp[0]);
            unsigned p23 = ((unsigned)(unsigned short)f2bf(hp[3]) << 16)
                         |  (unsigned)(unsigned short)f2bf(hp[2]);
            unsigned long long* hwr =
                hb3 + (size_t)((((t + 1) & 1) * 32 + b)) * 512 + (jq >> 1);
            __hip_atomic_store(hwr,     ((unsigned long long)p01 << 32) | tg1,
                               __ATOMIC_RELAXED, __HIP_MEMORY_SCOPE_AGENT);
            __hip_atomic_store(hwr + 1, ((unsigned long long)p23 << 32) | tg1,
                               __ATOMIC_RELAXED, __HIP_MEMORY_SCOPE_AGENT);
            if (l == 0)
                __hip_atomic_store(flags + w * 64 + bid, (unsigned)(t + 1),
                                   __ATOMIC_RELAXED, __HIP_MEMORY_SCOPE_AGENT);
        }

        // ---- 6. out stores + prefetch, strictly after publish ----
        float4 o4 = { hp[0], hp[1], hp[2], hp[3] };
        *reinterpret_cast<float4*>(out + (size_t)rowg * 1024 + jq) = o4;
        if (t == 511) {
            *reinterpret_cast<float4*>(out + 16777216 + b * 1024 + jq) = o4;
            *reinterpret_cast<float4*>(out + 16809984 + b * 1024 + jq) = o4;
        }

        if (t < 511) {
            const short* gp = gi + (size_t)((t + 1) * 32 + b) * 3072 + jq;
            gr_.u = *reinterpret_cast<const unsigned long long*>(gp);
            gz_.u = *reinterpret_cast<const unsigned long long*>(gp + 1024);
            gn_.u = *reinterpret_cast<const unsigned long long*>(gp + 2048);
            pv = pad[(t + 1) * 32 + b];
        }
    }
}

// ---------------------------------------------------------------------------
extern "C" void kernel_launch(void* const* d_in, const int* in_sizes, int n_in,
                              void* d_out, int out_size, void* d_ws, size_t ws_size,
                              hipStream_t stream) {
    const float* X   = (const float*)d_in[0];
    const float* pad = (const float*)d_in[1];
    const float* Wih = (const float*)d_in[2];
    const float* Whh = (const float*)d_in[3];
    const float* bih = (const float*)d_in[4];
    const float* bhh = (const float*)d_in[5];
    float* out = (float*)d_out;

    char* ws = (char*)d_ws;
    short*    gi    = (short*)(ws);                      // 100,663,296 B
    short*    Wih_t = (short*)(ws + 100663296);          //   6,291,456 B (dead after gemm)
    short*    Whh_t = (short*)(ws + 106954752);          //   6,291,456 B
    unsigned long long* hb3 =
        (unsigned long long*)(ws + 100663296);           // reuses Wih_t: 262,144 B
    unsigned* flags = (unsigned*)(ws + 100663296 + 262144);  // 512 B

    hipLaunchKernelGGL(k_transpose_bf16, dim3(1536), dim3(256), 0, stream, Wih, Wih_t);
    hipLaunchKernelGGL(k_transpose_bf16, dim3(1536), dim3(256), 0, stream, Whh, Whh_t);
    hipLaunchKernelGGL(k_gemm_gi, dim3(256 * 48), dim3(256), 0, stream, X, Wih_t, gi);

    // Zero the tagged-u64 buffer (h0 = 0, tags = 0 = valid step-0 state)
    // + flags. Enqueued AFTER the gemm so the Wih_t aliasing is stream-safe.
    hipMemsetAsync(hb3, 0, 262144 + 512, stream);

    hipFuncSetAttribute((const void*)k_gru,
                        hipFuncAttributeMaxDynamicSharedMemorySize, 99072);
    hipLaunchKernelGGL(k_gru, dim3(NB), dim3(128), 99072, stream,
                       pad, gi, Whh_t, bih, bhh, hb3, flags, out);
}